// Round 1
// baseline (6778.307 us; speedup 1.0000x reference)
//
#include <hip/hip_runtime.h>

#define NPTS 8192
#define NB 16
#define NS 1024
#define NK 32
#define NSAMP (NB*NS*NK)  // 524288
#define EPSBN 1e-5f

// ---------------------------------------------------------------------------
// FPS: one block per batch. Points in registers (8/thread), candidate
// (dist,idx,x,y,z) reduced via shfl + LDS. No-FMA distance math to mirror
// XLA elementwise semantics; ties -> smallest index (argmax first-occurrence).
// ---------------------------------------------------------------------------
__global__ __launch_bounds__(1024, 1) void fps_kernel(
    const float* __restrict__ xyz, float* __restrict__ newxyz, int* __restrict__ fpsi)
{
  const int b = blockIdx.x;
  const int tid = threadIdx.x;
  const float* xb = xyz + (size_t)b * NPTS * 3;
  float px[8], py[8], pz[8], dist[8];
#pragma unroll
  for (int j = 0; j < 8; ++j) {
    const int i = tid + j * 1024;
    px[j] = xb[3*i+0]; py[j] = xb[3*i+1]; pz[j] = xb[3*i+2];
    dist[j] = 1e10f;
  }
  __shared__ float rv[16], rx[16], ry[16], rz[16];
  __shared__ int   ri[16];
  __shared__ float cs[3];
  __shared__ int   curfar;
  if (tid == 0) { curfar = 0; cs[0] = px[0]; cs[1] = py[0]; cs[2] = pz[0]; }
  __syncthreads();
  for (int t = 0; t < NS; ++t) {
    const int far = curfar;
    const float cx = cs[0], cy = cs[1], cz = cs[2];
    if (tid == 0) {
      fpsi[b*NS + t] = far;
      newxyz[((size_t)b*NS + t)*3 + 0] = cx;
      newxyz[((size_t)b*NS + t)*3 + 1] = cy;
      newxyz[((size_t)b*NS + t)*3 + 2] = cz;
    }
    float bv = -1.0f, bx = 0.f, by = 0.f, bz = 0.f;
    int bi = 0;
#pragma unroll
    for (int j = 0; j < 8; ++j) {
      const float dx = __fsub_rn(px[j], cx);
      const float dy = __fsub_rn(py[j], cy);
      const float dz = __fsub_rn(pz[j], cz);
      const float d = __fadd_rn(__fadd_rn(__fmul_rn(dx,dx), __fmul_rn(dy,dy)), __fmul_rn(dz,dz));
      const float dj = fminf(dist[j], d);
      dist[j] = dj;
      const bool better = dj > bv;   // j ascending => index ascending => first-max kept
      bv = better ? dj : bv;
      bi = better ? (tid + j*1024) : bi;
      bx = better ? px[j] : bx;
      by = better ? py[j] : by;
      bz = better ? pz[j] : bz;
    }
#pragma unroll
    for (int off = 32; off >= 1; off >>= 1) {
      const float ov = __shfl_xor(bv, off);
      const int   oi = __shfl_xor(bi, off);
      const float ox = __shfl_xor(bx, off);
      const float oy = __shfl_xor(by, off);
      const float oz = __shfl_xor(bz, off);
      const bool take = (ov > bv) || ((ov == bv) && (oi < bi));
      bv = take ? ov : bv; bi = take ? oi : bi;
      bx = take ? ox : bx; by = take ? oy : by; bz = take ? oz : bz;
    }
    const int wid = tid >> 6;
    if ((tid & 63) == 0) { rv[wid]=bv; ri[wid]=bi; rx[wid]=bx; ry[wid]=by; rz[wid]=bz; }
    __syncthreads();
    if (tid < 64) {
      float v  = (tid < 16) ? rv[tid] : -2.0f;
      int   i2 = (tid < 16) ? ri[tid] : 0x7fffffff;
      float x2 = (tid < 16) ? rx[tid] : 0.f;
      float y2 = (tid < 16) ? ry[tid] : 0.f;
      float z2 = (tid < 16) ? rz[tid] : 0.f;
#pragma unroll
      for (int off = 8; off >= 1; off >>= 1) {
        const float ov = __shfl_xor(v, off);
        const int   oi = __shfl_xor(i2, off);
        const float ox = __shfl_xor(x2, off);
        const float oy = __shfl_xor(y2, off);
        const float oz = __shfl_xor(z2, off);
        const bool take = (ov > v) || ((ov == v) && (oi < i2));
        v = take ? ov : v; i2 = take ? oi : i2;
        x2 = take ? ox : x2; y2 = take ? oy : y2; z2 = take ? oz : z2;
      }
      if (tid == 0) { curfar = i2; cs[0] = x2; cs[1] = y2; cs[2] = z2; }
    }
    __syncthreads();
  }
}

// ---------------------------------------------------------------------------
// kNN: thread per (b,s) row; exact stable top-32 by (d, idx) via branchless
// unrolled insertion (all register indices static). xyz reads wave-uniform.
// ---------------------------------------------------------------------------
__global__ __launch_bounds__(256, 4) void knn_kernel(
    const float* __restrict__ xyz, const float* __restrict__ newxyz, int* __restrict__ gidx)
{
  const int row = blockIdx.x * 256 + threadIdx.x;
  const int b = blockIdx.x >> 2;   // 4 blocks per batch -> uniform per block
  const float* xb = xyz + (size_t)b * NPTS * 3;
  const float qx = newxyz[(size_t)row*3+0];
  const float qy = newxyz[(size_t)row*3+1];
  const float qz = newxyz[(size_t)row*3+2];
  const float ss = __fadd_rn(__fadd_rn(__fmul_rn(qx,qx), __fmul_rn(qy,qy)), __fmul_rn(qz,qz));
  float dl[NK]; int il[NK];
#pragma unroll
  for (int k = 0; k < NK; ++k) { dl[k] = 3.0e38f; il[k] = 0; }
  for (int i = 0; i < NPTS; ++i) {
    const float tx = xb[3*i+0], ty = xb[3*i+1], tz = xb[3*i+2];
    const float tt = __fadd_rn(__fadd_rn(__fmul_rn(tx,tx), __fmul_rn(ty,ty)), __fmul_rn(tz,tz));
    const float dt = __fadd_rn(__fadd_rn(__fmul_rn(qx,tx), __fmul_rn(qy,ty)), __fmul_rn(qz,tz));
    const float d = __fadd_rn(__fadd_rn(__fmul_rn(-2.0f, dt), ss), tt);
    if (d < dl[NK-1]) {
#pragma unroll
      for (int k = NK-1; k >= 1; --k) {
        const bool sh = d < dl[k-1];                 // strict: stable wrt equal values
        const bool pl = (d < dl[k]) && !sh;
        const float nd = sh ? dl[k-1] : dl[k];
        const int   ni = sh ? il[k-1] : il[k];
        dl[k] = pl ? d : nd;
        il[k] = pl ? i : ni;
      }
      const bool pl0 = d < dl[0];
      dl[0] = pl0 ? d : dl[0];
      il[0] = pl0 ? i : il[0];
    }
  }
#pragma unroll
  for (int k = 0; k < NK; ++k) gidx[(size_t)row*NK + k] = il[k];
}

// ---------------------------------------------------------------------------
// Build F0 = [grouped_xyz - new_xyz, grouped_points]  (524288 x 9) and
// accumulate 9-dim first/second moments (for layer-0 BN stats, since
// y0 = W0 f + b0 is linear in f).
// ---------------------------------------------------------------------------
__global__ __launch_bounds__(256, 4) void build_kernel(
    const float* __restrict__ xyz, const float* __restrict__ pts,
    const float* __restrict__ newxyz, const int* __restrict__ gidx,
    float* __restrict__ F0, float* __restrict__ stats0)
{
  float m1[9];
  float m2[45];
#pragma unroll
  for (int a = 0; a < 9; ++a) m1[a] = 0.f;
#pragma unroll
  for (int c = 0; c < 45; ++c) m2[c] = 0.f;
  const int tgid = blockIdx.x * 256 + threadIdx.x;
  for (int it = 0; it < 4; ++it) {
    const int smp = tgid + it * 131072;
    const int row = smp >> 5;
    const int b = row >> 10;
    const int gi = gidx[smp];
    const float* p3 = xyz + ((size_t)b*NPTS + gi)*3;
    const float* p6 = pts + ((size_t)b*NPTS + gi)*6;
    const float* q  = newxyz + (size_t)row*3;
    float f[9];
    f[0] = __fsub_rn(p3[0], q[0]);
    f[1] = __fsub_rn(p3[1], q[1]);
    f[2] = __fsub_rn(p3[2], q[2]);
#pragma unroll
    for (int c = 0; c < 6; ++c) f[3+c] = p6[c];
#pragma unroll
    for (int c = 0; c < 9; ++c) F0[(size_t)smp*9 + c] = f[c];
    int cnt = 0;
#pragma unroll
    for (int a = 0; a < 9; ++a) {
      m1[a] += f[a];
#pragma unroll
      for (int b2 = a; b2 < 9; ++b2) { m2[cnt] = fmaf(f[a], f[b2], m2[cnt]); ++cnt; }
    }
  }
#pragma unroll
  for (int off = 32; off >= 1; off >>= 1) {
#pragma unroll
    for (int a = 0; a < 9; ++a) m1[a] += __shfl_xor(m1[a], off);
#pragma unroll
    for (int c = 0; c < 45; ++c) m2[c] += __shfl_xor(m2[c], off);
  }
  __shared__ float sred[4][54];
  const int wid = threadIdx.x >> 6;
  if ((threadIdx.x & 63) == 0) {
#pragma unroll
    for (int a = 0; a < 9; ++a) sred[wid][a] = m1[a];
#pragma unroll
    for (int c = 0; c < 45; ++c) sred[wid][9+c] = m2[c];
  }
  __syncthreads();
  if (threadIdx.x < 54) {
    const float v = sred[0][threadIdx.x] + sred[1][threadIdx.x] +
                    sred[2][threadIdx.x] + sred[3][threadIdx.x];
    atomicAdd(&stats0[threadIdx.x], v);
  }
}

// ---------------------------------------------------------------------------
// BN parameter helpers (computed redundantly per block; cheap)
// ---------------------------------------------------------------------------
__device__ __forceinline__ void bn0_params(int c, const float* __restrict__ stats0,
    const float* __restrict__ w0, const float* __restrict__ b0,
    const float* __restrict__ g0, const float* __restrict__ bb0,
    float* sc, float* sf)
{
  const float invn = 1.0f / (float)NSAMP;
  float wv[9];
#pragma unroll
  for (int a = 0; a < 9; ++a) wv[a] = w0[c*9+a];
  float t = 0.f;
#pragma unroll
  for (int a = 0; a < 9; ++a) t = fmaf(wv[a], stats0[a], t);
  float q = 0.f;
  int cnt = 9;
#pragma unroll
  for (int a = 0; a < 9; ++a) {
#pragma unroll
    for (int b2 = a; b2 < 9; ++b2) {
      const float coef = (a == b2) ? (wv[a]*wv[a]) : (2.f*wv[a]*wv[b2]);
      q = fmaf(coef, stats0[cnt], q);
      ++cnt;
    }
  }
  const float tm = t * invn;
  const float mean = tm + b0[c];
  const float var = q * invn - tm*tm;     // b0 cancels in var
  const float scale = g0[c] / sqrtf(var + EPSBN);
  sc[c] = scale;
  sf[c] = fmaf(-mean, scale, bb0[c]);
}

__device__ __forceinline__ void bn_sums_params(int c, int C, const float* __restrict__ sums,
    const float* __restrict__ g, const float* __restrict__ bb, float* sc, float* sf)
{
  const float invn = 1.0f / (float)NSAMP;
  const float mean = sums[c] * invn;
  const float var = sums[C + c] * invn - mean*mean;
  const float scale = g[c] / sqrtf(var + EPSBN);
  sc[c] = scale;
  sf[c] = fmaf(-mean, scale, bb[c]);
}

__device__ __forceinline__ void compute_z0(const float* __restrict__ fr,
    const float* __restrict__ w0, const float* __restrict__ b0,
    const float* sc0, const float* sf0, float* z0)
{
#pragma unroll
  for (int c = 0; c < 64; ++c) {
    float y = b0[c];
#pragma unroll
    for (int a = 0; a < 9; ++a) y = fmaf(fr[a], w0[c*9+a], y);
    z0[c] = fmaxf(fmaf(y, sc0[c], sf0[c]), 0.f);
  }
}

// ---------------------------------------------------------------------------
// Pass B: z0 -> y1, accumulate per-channel sum/sumsq of y1 (layer-1 BN stats)
// ---------------------------------------------------------------------------
__global__ __launch_bounds__(256, 1) void passB_kernel(
    const float* __restrict__ F0, const float* __restrict__ stats0,
    const float* __restrict__ w0, const float* __restrict__ b0,
    const float* __restrict__ g0, const float* __restrict__ bb0,
    const float* __restrict__ w1, const float* __restrict__ b1,
    float* __restrict__ stats1)
{
  __shared__ float sc0[64], sf0[64];
  if (threadIdx.x < 64) bn0_params(threadIdx.x, stats0, w0, b0, g0, bb0, sc0, sf0);
  __syncthreads();
  float accS[64], accQ[64];
#pragma unroll
  for (int o = 0; o < 64; ++o) { accS[o]=0.f; accQ[o]=0.f; }
  const int tgid = blockIdx.x * 256 + threadIdx.x;
  for (int it = 0; it < 4; ++it) {
    const int smp = tgid + it * 131072;
    const float* f = F0 + (size_t)smp * 9;
    float fr[9];
#pragma unroll
    for (int a = 0; a < 9; ++a) fr[a] = f[a];
    float z0[64];
    compute_z0(fr, w0, b0, sc0, sf0, z0);
#pragma unroll
    for (int o = 0; o < 64; ++o) {
      float y = b1[o];
#pragma unroll
      for (int c = 0; c < 64; ++c) y = fmaf(z0[c], w1[o*64+c], y);
      accS[o] += y;
      accQ[o] = fmaf(y, y, accQ[o]);
    }
  }
#pragma unroll
  for (int off = 32; off >= 1; off >>= 1) {
#pragma unroll
    for (int o = 0; o < 64; ++o) {
      accS[o] += __shfl_xor(accS[o], off);
      accQ[o] += __shfl_xor(accQ[o], off);
    }
  }
  __shared__ float sred[4][128];
  const int wid = threadIdx.x >> 6;
  if ((threadIdx.x & 63) == 0) {
#pragma unroll
    for (int o = 0; o < 64; ++o) { sred[wid][o] = accS[o]; sred[wid][64+o] = accQ[o]; }
  }
  __syncthreads();
  if (threadIdx.x < 128) {
    const float v = sred[0][threadIdx.x] + sred[1][threadIdx.x] +
                    sred[2][threadIdx.x] + sred[3][threadIdx.x];
    atomicAdd(&stats1[threadIdx.x], v);
  }
}

// ---------------------------------------------------------------------------
// Pass C: z0 -> z1 -> y2, accumulate per-channel sum/sumsq of y2
// ---------------------------------------------------------------------------
__global__ __launch_bounds__(256, 2) void passC_kernel(
    const float* __restrict__ F0, const float* __restrict__ stats0, const float* __restrict__ stats1,
    const float* __restrict__ w0, const float* __restrict__ b0, const float* __restrict__ g0, const float* __restrict__ bb0,
    const float* __restrict__ w1, const float* __restrict__ b1, const float* __restrict__ g1, const float* __restrict__ bb1,
    const float* __restrict__ w2, const float* __restrict__ b2,
    float* __restrict__ stats2)
{
  __shared__ float sc0[64], sf0[64], sc1[64], sf1[64];
  __shared__ float swacc[4][256];
  if (threadIdx.x < 64) bn0_params(threadIdx.x, stats0, w0, b0, g0, bb0, sc0, sf0);
  else if (threadIdx.x < 128) bn_sums_params(threadIdx.x-64, 64, stats1, g1, bb1, sc1, sf1);
  {
    float* sw = &swacc[0][0];
    for (int idx = threadIdx.x; idx < 1024; idx += 256) sw[idx] = 0.f;
  }
  __syncthreads();
  const int tgid = blockIdx.x * 256 + threadIdx.x;
  const int wid = threadIdx.x >> 6;
  for (int it = 0; it < 4; ++it) {
    const int smp = tgid + it * 131072;
    const float* f = F0 + (size_t)smp * 9;
    float fr[9];
#pragma unroll
    for (int a = 0; a < 9; ++a) fr[a] = f[a];
    float z0[64];
    compute_z0(fr, w0, b0, sc0, sf0, z0);
    float z1[64];
#pragma unroll
    for (int o = 0; o < 64; ++o) {
      float y = b1[o];
#pragma unroll
      for (int c = 0; c < 64; ++c) y = fmaf(z0[c], w1[o*64+c], y);
      z1[o] = fmaxf(fmaf(y, sc1[o], sf1[o]), 0.f);
    }
    for (int oo = 0; oo < 128; ++oo) {   // dynamic loop: y2 consumed immediately
      float y = b2[oo];
#pragma unroll
      for (int c = 0; c < 64; ++c) y = fmaf(z1[c], w2[oo*64+c], y);
      float yq = __fmul_rn(y, y);
      float ysv = y;
#pragma unroll
      for (int off = 32; off >= 1; off >>= 1) {
        ysv += __shfl_xor(ysv, off);
        yq  += __shfl_xor(yq, off);
      }
      if ((threadIdx.x & 63) == 0) { swacc[wid][oo] += ysv; swacc[wid][128+oo] += yq; }
    }
  }
  __syncthreads();
  {
    const float v = swacc[0][threadIdx.x] + swacc[1][threadIdx.x] +
                    swacc[2][threadIdx.x] + swacc[3][threadIdx.x];
    atomicAdd(&stats2[threadIdx.x], v);
  }
}

// ---------------------------------------------------------------------------
// Pass D: full pipeline + max over K (32 consecutive lanes) -> new_points
// ---------------------------------------------------------------------------
__global__ __launch_bounds__(256, 2) void passD_kernel(
    const float* __restrict__ F0, const float* __restrict__ stats0,
    const float* __restrict__ stats1, const float* __restrict__ stats2,
    const float* __restrict__ w0, const float* __restrict__ b0, const float* __restrict__ g0, const float* __restrict__ bb0,
    const float* __restrict__ w1, const float* __restrict__ b1, const float* __restrict__ g1, const float* __restrict__ bb1,
    const float* __restrict__ w2, const float* __restrict__ b2, const float* __restrict__ g2, const float* __restrict__ bb2,
    float* __restrict__ outnp)
{
  __shared__ float sc0[64], sf0[64], sc1[64], sf1[64], sc2[128], sf2[128];
  if (threadIdx.x < 64) bn0_params(threadIdx.x, stats0, w0, b0, g0, bb0, sc0, sf0);
  else if (threadIdx.x < 128) bn_sums_params(threadIdx.x-64, 64, stats1, g1, bb1, sc1, sf1);
  else bn_sums_params(threadIdx.x-128, 128, stats2, g2, bb2, sc2, sf2);
  __syncthreads();
  const int smp = blockIdx.x * 256 + threadIdx.x;
  const float* f = F0 + (size_t)smp * 9;
  float fr[9];
#pragma unroll
  for (int a = 0; a < 9; ++a) fr[a] = f[a];
  float z0[64];
  compute_z0(fr, w0, b0, sc0, sf0, z0);
  float z1[64];
#pragma unroll
  for (int o = 0; o < 64; ++o) {
    float y = b1[o];
#pragma unroll
    for (int c = 0; c < 64; ++c) y = fmaf(z0[c], w1[o*64+c], y);
    z1[o] = fmaxf(fmaf(y, sc1[o], sf1[o]), 0.f);
  }
  const int row = smp >> 5;
  const bool leader = (threadIdx.x & 31) == 0;
  for (int oo = 0; oo < 128; ++oo) {
    float y = b2[oo];
#pragma unroll
    for (int c = 0; c < 64; ++c) y = fmaf(z1[c], w2[oo*64+c], y);
    float z2 = fmaxf(fmaf(y, sc2[oo], sf2[oo]), 0.f);
#pragma unroll
    for (int off = 16; off >= 1; off >>= 1) z2 = fmaxf(z2, __shfl_xor(z2, off));
    if (leader) outnp[(size_t)row*128 + oo] = z2;
  }
}

// ---------------------------------------------------------------------------
extern "C" void kernel_launch(void* const* d_in, const int* in_sizes, int n_in,
                              void* d_out, int out_size, void* d_ws, size_t ws_size,
                              hipStream_t stream)
{
  const float* xyz = (const float*)d_in[0];
  const float* pts = (const float*)d_in[1];
  const float* w0  = (const float*)d_in[2];
  const float* b0  = (const float*)d_in[3];
  const float* g0  = (const float*)d_in[4];
  const float* bb0 = (const float*)d_in[5];
  const float* w1  = (const float*)d_in[6];
  const float* b1  = (const float*)d_in[7];
  const float* g1  = (const float*)d_in[8];
  const float* bb1 = (const float*)d_in[9];
  const float* w2  = (const float*)d_in[10];
  const float* b2  = (const float*)d_in[11];
  const float* g2  = (const float*)d_in[12];
  const float* bb2 = (const float*)d_in[13];

  float* out    = (float*)d_out;
  float* newxyz = out;                     // [16,1024,3]
  float* outnp  = out + (size_t)NB*NS*3;   // [16,1024,128]

  char* ws = (char*)d_ws;
  int*   fpsi   = (int*)(ws);
  int*   gidx   = (int*)(ws + 65536);
  float* F0     = (float*)(ws + 65536 + 2097152);
  float* stats  = (float*)(ws + 65536 + 2097152 + 18874368);
  float* stats0 = stats;            // 54 (padded to 64)
  float* stats1 = stats + 64;       // 128
  float* stats2 = stats + 64 + 128; // 256
  const size_t needed = 65536 + 2097152 + 18874368 + (64+128+256)*sizeof(float);
  if (ws_size < needed) return;

  hipMemsetAsync(stats, 0, (64+128+256)*sizeof(float), stream);
  fps_kernel  <<<NB,   1024, 0, stream>>>(xyz, newxyz, fpsi);
  knn_kernel  <<<64,   256,  0, stream>>>(xyz, newxyz, gidx);
  build_kernel<<<512,  256,  0, stream>>>(xyz, pts, newxyz, gidx, F0, stats0);
  passB_kernel<<<512,  256,  0, stream>>>(F0, stats0, w0, b0, g0, bb0, w1, b1, stats1);
  passC_kernel<<<512,  256,  0, stream>>>(F0, stats0, stats1, w0, b0, g0, bb0,
                                          w1, b1, g1, bb1, w2, b2, stats2);
  passD_kernel<<<2048, 256,  0, stream>>>(F0, stats0, stats1, stats2, w0, b0, g0, bb0,
                                          w1, b1, g1, bb1, w2, b2, g2, bb2, outnp);
}